// Round 3
// baseline (148.461 us; speedup 1.0000x reference)
//
#include <hip/hip_runtime.h>
#include <hip/hip_bf16.h>
#include <stdint.h>

#define HWN 50176   // 224*224
#define NM  1000
#define FD  128
#define NSPLIT 49
#define KSTEPS 32
#define NSCAN 20
#define NPB 50      // 1000 / 20

typedef __attribute__((ext_vector_type(8))) short short8;
typedef __attribute__((ext_vector_type(4))) float f32x4;

__device__ __forceinline__ unsigned short f2bf(float x) {
    union { float f; unsigned u; } v; v.f = x;
    unsigned r = v.u + 0x7FFFu + ((v.u >> 16) & 1u);
    return (unsigned short)(r >> 16);
}

#define AS1(p) ((const __attribute__((address_space(1))) unsigned int*)(p))
#define AS3(p) ((__attribute__((address_space(3))) unsigned int*)(p))

// Stage 1: A[hw,f] = sum_c img*W, written as swizzled bf16 k-tiles:
// tile kt covers k in [kt*32, kt*32+32); 8192B: row f (64B), 16B chunk j at
// slot (j ^ (f&3)).  Also fp32 per-block rep0 partials.
__global__ __launch_bounds__(256) void k_encode(const float* __restrict__ img,
                                                const float* __restrict__ Wt,
                                                unsigned short* __restrict__ Bpack,
                                                float* __restrict__ rep0part)
{
    const int t = threadIdx.x;
    const int f = t & 127;
    const int kt = blockIdx.x * 2 + (t >> 7);
    const int hw0 = kt * 32;
    float vals[32];
    float rsum = 0.f;
#pragma unroll
    for (int e = 0; e < 32; ++e) {
        const int hw = hw0 + e;
        float a = img[hw] * Wt[(size_t)hw * FD + f];
        a = fmaf(img[HWN + hw],     Wt[(size_t)(HWN + hw) * FD + f], a);
        a = fmaf(img[2 * HWN + hw], Wt[(size_t)(2 * HWN + hw) * FD + f], a);
        vals[e] = a;
        rsum += a;
    }
    char* tile = (char*)Bpack + (size_t)kt * 8192 + f * 64;
#pragma unroll
    for (int j = 0; j < 4; ++j) {
        short8 pk;
#pragma unroll
        for (int e = 0; e < 8; ++e) pk[e] = (short)f2bf(vals[j * 8 + e]);
        *reinterpret_cast<short8*>(tile + ((j ^ (f & 3)) << 4)) = pk;
    }
    __shared__ float red[256];
    red[t] = rsum;
    __syncthreads();
    if (t < 128) rep0part[(size_t)blockIdx.x * 128 + f] = red[t] + red[t + 128];
}

// Stage 2: rep0[f] = sum of 784 partials
__global__ __launch_bounds__(256) void k_rep0red(const float* __restrict__ rep0part,
                                                 float* __restrict__ rep0)
{
    const int f = blockIdx.x;
    float s = 0.f;
    for (int b = threadIdx.x; b < 784; b += 256) s += rep0part[(size_t)b * 128 + f];
    __shared__ float red[256];
    red[threadIdx.x] = s;
    __syncthreads();
    for (int o = 128; o > 0; o >>= 1) {
        if (threadIdx.x < o) red[threadIdx.x] += red[threadIdx.x + o];
        __syncthreads();
    }
    if (threadIdx.x == 0) rep0[f] = red[0];
}

// Stage 3: split-K GEMM, 64-row M-tile, 4 waves / 256 threads, grid 16x49=784
// (3.06 blocks/CU: balanced). B double-buffered via global_load_lds (swizzled
// pack); A (masks) global->reg->cvt_pk bf16.
__global__ __launch_bounds__(256, 4) void k_gemm(const float* __restrict__ masks,
                                                 const unsigned short* __restrict__ Bpack,
                                                 float* __restrict__ partial)
{
    __shared__ __align__(16) unsigned short Bs[2][4096];   // 2 x 8192 B

    const int t = threadIdx.x;
    const int wv = t >> 6, lane = t & 63;
    const int lrow = lane & 15, lslot = lane >> 4;
    const int mtile = blockIdx.x, split = blockIdx.y;

    int row = mtile * 64 + wv * 16 + lrow;
    if (row >= NM) row = NM - 1;                  // clamp: rows >=1000 never read back
    const float* aptr = masks + (size_t)row * HWN + split * 1024 + lslot * 8;
    // 256 threads stage 8192B: 2x16B per thread
    const char* bsrc = (const char*)Bpack + (size_t)(split * KSTEPS) * 8192 + t * 16;
    char* dst0 = (char*)&Bs[0][0] + t * 16;
    char* dst1 = (char*)&Bs[1][0] + t * 16;
    const int rdoff = lrow * 64 + ((lslot ^ (lrow & 3)) << 4);

    f32x4 acc[8];
#pragma unroll
    for (int i = 0; i < 8; ++i) acc[i] = f32x4{0.f, 0.f, 0.f, 0.f};

    // prologue: B(0) DMA + A(0) reg loads
    __builtin_amdgcn_global_load_lds(AS1(bsrc), AS3(dst0), 16, 0, 0);
    __builtin_amdgcn_global_load_lds(AS1(bsrc + 4096), AS3(dst0 + 4096), 16, 0, 0);
    f32x4 a0 = *reinterpret_cast<const f32x4*>(aptr);
    f32x4 a1 = *reinterpret_cast<const f32x4*>(aptr + 4);

    for (int ks = 0; ks < KSTEPS; ++ks) {
        const int cur = ks & 1;
        __syncthreads();   // drains vmcnt/lgkm: B(ks) in LDS, A(ks) in regs
        if (ks + 1 < KSTEPS) {
            char* nd = cur ? dst0 : dst1;
            const char* nsrc = bsrc + (size_t)(ks + 1) * 8192;
            __builtin_amdgcn_global_load_lds(AS1(nsrc), AS3(nd), 16, 0, 0);
            __builtin_amdgcn_global_load_lds(AS1(nsrc + 4096), AS3(nd + 4096), 16, 0, 0);
        }
        const int kn = (ks + 1 < KSTEPS) ? (ks + 1) : ks;
        f32x4 na0 = *reinterpret_cast<const f32x4*>(aptr + kn * 32);
        f32x4 na1 = *reinterpret_cast<const f32x4*>(aptr + kn * 32 + 4);

        union { short8 s; __hip_bfloat162 h[4]; } apk;
        apk.h[0] = __float22bfloat162_rn(float2{a0[0], a0[1]});
        apk.h[1] = __float22bfloat162_rn(float2{a0[2], a0[3]});
        apk.h[2] = __float22bfloat162_rn(float2{a1[0], a1[1]});
        apk.h[3] = __float22bfloat162_rn(float2{a1[2], a1[3]});

        const char* bbase = (const char*)&Bs[cur][0] + rdoff;
#pragma unroll
        for (int ft = 0; ft < 8; ++ft) {
            short8 bfv = *reinterpret_cast<const short8*>(bbase + ft * 1024);
            acc[ft] = __builtin_amdgcn_mfma_f32_16x16x32_bf16(apk.s, bfv, acc[ft], 0, 0, 0);
        }
        a0 = na0; a1 = na1;
    }

    // epilogue: C row = mtile*64 + wv*16 + lslot*4 + r, col = ft*16 + lrow
    const int crow = mtile * 64 + wv * 16 + (lslot << 2);
    float* pb = partial + ((size_t)split * 1024 + crow) * FD + lrow;
#pragma unroll
    for (int ft = 0; ft < 8; ++ft)
#pragma unroll
        for (int r = 0; r < 4; ++r)
            __builtin_nontemporal_store(acc[ft][r], pb + (size_t)r * FD + ft * 16);
}

// Stage 4: reduce split-K partials (nt loads: don't evict masks), cosine sim
__global__ __launch_bounds__(128) void k_sims(const float* __restrict__ partial,
                                              const float* __restrict__ rep0,
                                              float* __restrict__ sims)
{
    const int n = blockIdx.x;
    const int f = threadIdx.x;
    float r = 0.f;
    for (int s = 0; s < NSPLIT; ++s)
        r += __builtin_nontemporal_load(partial + ((size_t)s * 1024 + n) * FD + f);
    const float r0 = rep0[f];
    __shared__ float red0[128], red1[128], red2[128];
    red0[f] = r * r0;
    red1[f] = r * r;
    red2[f] = r0 * r0;
    __syncthreads();
    for (int o = 64; o > 0; o >>= 1) {
        if (f < o) {
            red0[f] += red0[f + o];
            red1[f] += red1[f + o];
            red2[f] += red2[f + o];
        }
        __syncthreads();
    }
    if (f == 0) {
        const float nr = fmaxf(sqrtf(red1[0]), 1e-8f);
        const float nz = fmaxf(sqrtf(red2[0]), 1e-8f);
        sims[n] = red0[0] / (nr * nz);
    }
}

// Stage 5a: per-pixel weighted sums S0,S1,S2 over an n-chunk, float4 pixels
__global__ __launch_bounds__(256) void k_colsums(const float* __restrict__ masks,
                                                 const float* __restrict__ sims,
                                                 float* __restrict__ Spart)
{
    __shared__ float s1v[NPB], s2v[NPB];
    const int t = threadIdx.x;
    const int split = blockIdx.y;
    if (t < NPB) {
        const float s = sims[split * NPB + t];
        s1v[t] = s;
        s2v[t] = s * s;
    }
    __syncthreads();
    const int pix = (blockIdx.x * 256 + t) * 4;
    const float* mp = masks + (size_t)split * NPB * HWN + pix;
    f32x4 s0 = {0.f,0.f,0.f,0.f}, s1 = s0, s2 = s0;
#pragma unroll 5
    for (int i = 0; i < NPB; ++i) {
        const f32x4 m = *reinterpret_cast<const f32x4*>(mp + (size_t)i * HWN);
        const float a = s1v[i], b = s2v[i];
        s0 += m;
#pragma unroll
        for (int e = 0; e < 4; ++e) {
            s1[e] = fmaf(m[e], a, s1[e]);
            s2[e] = fmaf(m[e], b, s2[e]);
        }
    }
    float* sp = Spart + (size_t)split * 3 * HWN + pix;
    __builtin_nontemporal_store(s0, reinterpret_cast<f32x4*>(sp));
    __builtin_nontemporal_store(s1, reinterpret_cast<f32x4*>(sp + HWN));
    __builtin_nontemporal_store(s2, reinterpret_cast<f32x4*>(sp + 2 * HWN));
}

// Stage 5b: combine splits, closed-form imp/unc/sow
__global__ __launch_bounds__(256) void k_final(const float* __restrict__ Spart,
                                               float* __restrict__ out)
{
    const int pix = (blockIdx.x * 256 + threadIdx.x) * 4;
    f32x4 s0 = {0.f,0.f,0.f,0.f}, s1 = s0, s2 = s0;
#pragma unroll 4
    for (int sp = 0; sp < NSCAN; ++sp) {
        const float* p = Spart + (size_t)sp * 3 * HWN + pix;
        s0 += __builtin_nontemporal_load(reinterpret_cast<const f32x4*>(p));
        s1 += __builtin_nontemporal_load(reinterpret_cast<const f32x4*>(p + HWN));
        s2 += __builtin_nontemporal_load(reinterpret_cast<const f32x4*>(p + 2 * HWN));
    }
    f32x4 imp, unc, sow;
#pragma unroll
    for (int e = 0; e < 4; ++e) {
        sow[e] = 1e-10f + s0[e];
        imp[e] = s1[e] / sow[e];
        unc[e] = fmaf(-imp[e], s1[e], s2[e]);   // S2 - S1^2/sow
    }
    *reinterpret_cast<f32x4*>(out + pix) = imp;
    *reinterpret_cast<f32x4*>(out + HWN + pix) = unc;
    *reinterpret_cast<f32x4*>(out + 2 * HWN + pix) = sow;
}

extern "C" void kernel_launch(void* const* d_in, const int* in_sizes, int n_in,
                              void* d_out, int out_size, void* d_ws, size_t ws_size,
                              hipStream_t stream) {
    const float* img   = (const float*)d_in[0];
    const float* masks = (const float*)d_in[1];
    const float* Wt    = (const float*)d_in[2];
    float* out = (float*)d_out;

    char* ws = (char*)d_ws;
    unsigned short* Bpack = (unsigned short*)ws;                 // 12,845,056 B
    float* partial  = (float*)(ws + 12845056);                   // 25,690,112 B
    float* rep0part = partial;                                   // alias: consumed before gemm writes
    float* rep0     = (float*)(ws + 38535168);                   // 512 B
    float* sims     = (float*)(ws + 38535680);                   // 4,000 B
    float* Spart    = (float*)ws;                                // alias Bpack: gemm done by then (12,042,240 B)

    hipLaunchKernelGGL(k_encode,  dim3(784), dim3(256), 0, stream, img, Wt, Bpack, rep0part);
    hipLaunchKernelGGL(k_rep0red, dim3(128), dim3(256), 0, stream, rep0part, rep0);
    hipLaunchKernelGGL(k_gemm,    dim3(16, NSPLIT), dim3(256), 0, stream, masks, Bpack, partial);
    hipLaunchKernelGGL(k_sims,    dim3(NM), dim3(128), 0, stream, partial, rep0, sims);
    hipLaunchKernelGGL(k_colsums, dim3(49, NSCAN), dim3(256), 0, stream, masks, sims, Spart);
    hipLaunchKernelGGL(k_final,   dim3(49), dim3(256), 0, stream, Spart, out);
}

// Round 4
// 131.078 us; speedup vs baseline: 1.1326x; 1.1326x over previous
//
#include <hip/hip_runtime.h>
#include <hip/hip_bf16.h>
#include <stdint.h>

#define HWN 50176   // 224*224
#define NM  1000
#define FD  128
#define NSPLIT 49
#define KSTEPS 32
#define NSCAN 20
#define NPB 50      // 1000 / 20

typedef __attribute__((ext_vector_type(8))) short short8;
typedef __attribute__((ext_vector_type(4))) float f32x4;

__device__ __forceinline__ unsigned short f2bf(float x) {
    union { float f; unsigned u; } v; v.f = x;
    unsigned r = v.u + 0x7FFFu + ((v.u >> 16) & 1u);
    return (unsigned short)(r >> 16);
}

#define AS1(p) ((const __attribute__((address_space(1))) unsigned int*)(p))
#define AS3(p) ((__attribute__((address_space(3))) unsigned int*)(p))

// Stage 1: A[hw,f] = sum_c img*W, packed bf16 k-tiles for the GEMM B operand.
// Tile kt (8192B) = exact LDS image: 16B slot s = c*128 + ((f+c)&127), holding
// chunk c (k = kt*32 + c*8 .. +8) of feature f. Rotation de-phases the 4
// k-groups' bank patterns for conflict-free ds_read_b128.
__global__ __launch_bounds__(256) void k_encode(const float* __restrict__ img,
                                                const float* __restrict__ Wt,
                                                unsigned short* __restrict__ Bpack,
                                                float* __restrict__ rep0part)
{
    const int t = threadIdx.x;
    const int f = t & 127;
    const int kt = blockIdx.x * 2 + (t >> 7);
    const int hw0 = kt * 32;
    float vals[32];
    float rsum = 0.f;
#pragma unroll
    for (int e = 0; e < 32; ++e) {
        const int hw = hw0 + e;
        float a = img[hw] * Wt[(size_t)hw * FD + f];
        a = fmaf(img[HWN + hw],     Wt[(size_t)(HWN + hw) * FD + f], a);
        a = fmaf(img[2 * HWN + hw], Wt[(size_t)(2 * HWN + hw) * FD + f], a);
        vals[e] = a;
        rsum += a;
    }
    char* tile = (char*)Bpack + (size_t)kt * 8192;
#pragma unroll
    for (int j = 0; j < 4; ++j) {
        short8 pk;
#pragma unroll
        for (int e = 0; e < 8; ++e) pk[e] = (short)f2bf(vals[j * 8 + e]);
        *reinterpret_cast<short8*>(tile + j * 2048 + (((f + j) & 127) << 4)) = pk;
    }
    __shared__ float red[256];
    red[t] = rsum;
    __syncthreads();
    if (t < 128) rep0part[(size_t)blockIdx.x * 128 + f] = red[t] + red[t + 128];
}

// Stage 2: rep0[f] = sum of 784 partials
__global__ __launch_bounds__(256) void k_rep0red(const float* __restrict__ rep0part,
                                                 float* __restrict__ rep0)
{
    const int f = blockIdx.x;
    float s = 0.f;
    for (int b = threadIdx.x; b < 784; b += 256) s += rep0part[(size_t)b * 128 + f];
    __shared__ float red[256];
    red[threadIdx.x] = s;
    __syncthreads();
    for (int o = 128; o > 0; o >>= 1) {
        if (threadIdx.x < o) red[threadIdx.x] += red[threadIdx.x + o];
        __syncthreads();
    }
    if (threadIdx.x == 0) rep0[f] = red[0];
}

// Stage 3: split-K GEMM, 64-row M-tile, 4 waves, grid 16x49.
// Counted-vmcnt 3-buffer pipeline: stage step ks+2 while computing ks;
// end-of-iter s_waitcnt vmcnt(4) (never 0 in steady state) + raw s_barrier.
// All K-loop vmem goes through global_load_lds -> manual counts are exact.
__global__ __launch_bounds__(256, 3) void k_gemm(const float* __restrict__ masks,
                                                 const unsigned short* __restrict__ Bpack,
                                                 float* __restrict__ partial)
{
    __shared__ __align__(16) char lds[3][16384];   // per buf: A fp32 8KB | B bf16 8KB

    const int t = threadIdx.x;
    const int wv = t >> 6, lane = t & 63;
    const int lrow = lane & 15, kg = lane >> 4;
    const int mtile = blockIdx.x, split = blockIdx.y;
    const int n0 = mtile * 64;

    // ---- A staging geometry: 2 ops, LDS slot s = h*256 + t (linear),
    // slot s holds source chunk c = (s&7)^(row&7) of mask row (n0 + s>>3).
    const int s1 = 256 + t;
    const int ar0 = t >> 3, ar1 = s1 >> 3;
    const int ac0 = (t & 7) ^ (ar0 & 7);
    const int ac1 = (t & 7) ^ (ar1 & 7);
    int arow0 = n0 + ar0; if (arow0 >= NM) arow0 = NM - 1;   // clamped rows never read back
    int arow1 = n0 + ar1; if (arow1 >= NM) arow1 = NM - 1;
    const float* aSrc0 = masks + (size_t)arow0 * HWN + split * 1024 + ac0 * 4;
    const float* aSrc1 = masks + (size_t)arow1 * HWN + split * 1024 + ac1 * 4;
    const char*  bSrc  = (const char*)Bpack + (size_t)split * KSTEPS * 8192 + t * 16;

    // ---- fragment read offsets (loop-invariant per lane)
    const int r = wv * 16 + lrow;
    const int ao0 = r * 128 + (((2 * kg)     ^ (r & 7)) << 4);
    const int ao1 = r * 128 + ((((2 * kg)+1) ^ (r & 7)) << 4);
    int bo[8];
#pragma unroll
    for (int ft = 0; ft < 8; ++ft)
        bo[ft] = 8192 + kg * 2048 + (((ft * 16 + lrow + kg) & 127) << 4);

    f32x4 acc[8];
#pragma unroll
    for (int i = 0; i < 8; ++i) acc[i] = f32x4{0.f, 0.f, 0.f, 0.f};

#define STAGE(KS, BUF) do {                                                             \
        char* base_ = &lds[BUF][0];                                                     \
        __builtin_amdgcn_global_load_lds(AS1(aSrc0 + (KS) * 32), AS3(base_ + t * 16), 16, 0, 0);          \
        __builtin_amdgcn_global_load_lds(AS1(aSrc1 + (KS) * 32), AS3(base_ + 4096 + t * 16), 16, 0, 0);   \
        __builtin_amdgcn_global_load_lds(AS1(bSrc + (size_t)(KS) * 8192),        AS3(base_ + 8192 + t * 16), 16, 0, 0);        \
        __builtin_amdgcn_global_load_lds(AS1(bSrc + (size_t)(KS) * 8192 + 4096), AS3(base_ + 12288 + t * 16), 16, 0, 0);       \
    } while (0)

    STAGE(0, 0);
    STAGE(1, 1);
    asm volatile("s_waitcnt vmcnt(4)" ::: "memory");   // step0 landed; step1 in flight
    __builtin_amdgcn_s_barrier();
    __builtin_amdgcn_sched_barrier(0);

    int cur = 0, stg = 2;
    for (int ks = 0; ks < KSTEPS; ++ks) {
        if (ks + 2 < KSTEPS) STAGE(ks + 2, stg);

        const char* A = &lds[cur][0];
        const f32x4 alo = *reinterpret_cast<const f32x4*>(A + ao0);
        const f32x4 ahi = *reinterpret_cast<const f32x4*>(A + ao1);
        union { short8 s; __hip_bfloat162 h[4]; } apk;
        apk.h[0] = __float22bfloat162_rn(float2{alo[0], alo[1]});
        apk.h[1] = __float22bfloat162_rn(float2{alo[2], alo[3]});
        apk.h[2] = __float22bfloat162_rn(float2{ahi[0], ahi[1]});
        apk.h[3] = __float22bfloat162_rn(float2{ahi[2], ahi[3]});
        short8 bfv[8];
#pragma unroll
        for (int ft = 0; ft < 8; ++ft)
            bfv[ft] = *reinterpret_cast<const short8*>(A + bo[ft]);

        asm volatile("s_waitcnt lgkmcnt(0)" ::: "memory");
        __builtin_amdgcn_sched_barrier(0);
        __builtin_amdgcn_s_setprio(1);
#pragma unroll
        for (int ft = 0; ft < 8; ++ft)
            acc[ft] = __builtin_amdgcn_mfma_f32_16x16x32_bf16(apk.s, bfv[ft], acc[ft], 0, 0, 0);
        __builtin_amdgcn_s_setprio(0);
        __builtin_amdgcn_sched_barrier(0);

        if (ks < KSTEPS - 2)       asm volatile("s_waitcnt vmcnt(4)" ::: "memory");  // step ks+1 landed
        else if (ks == KSTEPS - 2) asm volatile("s_waitcnt vmcnt(0)" ::: "memory");  // tail drain
        if (ks < KSTEPS - 1) {
            __builtin_amdgcn_s_barrier();
            __builtin_amdgcn_sched_barrier(0);
        }
        cur = (cur + 1 == 3) ? 0 : cur + 1;
        stg = (stg + 1 == 3) ? 0 : stg + 1;
    }
#undef STAGE

    // epilogue: C row = n0 + wv*16 + kg*4 + r, col = ft*16 + lrow
    const int crow = n0 + wv * 16 + (kg << 2);
    float* pb = partial + ((size_t)split * 1024 + crow) * FD + lrow;
#pragma unroll
    for (int ft = 0; ft < 8; ++ft)
#pragma unroll
        for (int rr = 0; rr < 4; ++rr)
            __builtin_nontemporal_store(acc[ft][rr], pb + (size_t)rr * FD + ft * 16);
}

// Stage 4: reduce split-K partials (nt loads: don't evict masks), cosine sim
__global__ __launch_bounds__(128) void k_sims(const float* __restrict__ partial,
                                              const float* __restrict__ rep0,
                                              float* __restrict__ sims)
{
    const int n = blockIdx.x;
    const int f = threadIdx.x;
    float rsum = 0.f;
    for (int s = 0; s < NSPLIT; ++s)
        rsum += __builtin_nontemporal_load(partial + ((size_t)s * 1024 + n) * FD + f);
    const float r0 = rep0[f];
    __shared__ float red0[128], red1[128], red2[128];
    red0[f] = rsum * r0;
    red1[f] = rsum * rsum;
    red2[f] = r0 * r0;
    __syncthreads();
    for (int o = 64; o > 0; o >>= 1) {
        if (f < o) {
            red0[f] += red0[f + o];
            red1[f] += red1[f + o];
            red2[f] += red2[f + o];
        }
        __syncthreads();
    }
    if (f == 0) {
        const float nr = fmaxf(sqrtf(red1[0]), 1e-8f);
        const float nz = fmaxf(sqrtf(red2[0]), 1e-8f);
        sims[n] = red0[0] / (nr * nz);
    }
}

// Stage 5a: per-pixel weighted sums S0,S1,S2 over an n-chunk, float4 pixels
__global__ __launch_bounds__(256) void k_colsums(const float* __restrict__ masks,
                                                 const float* __restrict__ sims,
                                                 float* __restrict__ Spart)
{
    __shared__ float s1v[NPB], s2v[NPB];
    const int t = threadIdx.x;
    const int split = blockIdx.y;
    if (t < NPB) {
        const float s = sims[split * NPB + t];
        s1v[t] = s;
        s2v[t] = s * s;
    }
    __syncthreads();
    const int pix = (blockIdx.x * 256 + t) * 4;
    const float* mp = masks + (size_t)split * NPB * HWN + pix;
    f32x4 s0 = {0.f,0.f,0.f,0.f}, s1 = s0, s2 = s0;
#pragma unroll 5
    for (int i = 0; i < NPB; ++i) {
        const f32x4 m = *reinterpret_cast<const f32x4*>(mp + (size_t)i * HWN);
        const float a = s1v[i], b = s2v[i];
        s0 += m;
#pragma unroll
        for (int e = 0; e < 4; ++e) {
            s1[e] = fmaf(m[e], a, s1[e]);
            s2[e] = fmaf(m[e], b, s2[e]);
        }
    }
    float* sp = Spart + (size_t)split * 3 * HWN + pix;
    __builtin_nontemporal_store(s0, reinterpret_cast<f32x4*>(sp));
    __builtin_nontemporal_store(s1, reinterpret_cast<f32x4*>(sp + HWN));
    __builtin_nontemporal_store(s2, reinterpret_cast<f32x4*>(sp + 2 * HWN));
}

// Stage 5b: combine splits, closed-form imp/unc/sow
__global__ __launch_bounds__(256) void k_final(const float* __restrict__ Spart,
                                               float* __restrict__ out)
{
    const int pix = (blockIdx.x * 256 + threadIdx.x) * 4;
    f32x4 s0 = {0.f,0.f,0.f,0.f}, s1 = s0, s2 = s0;
#pragma unroll 4
    for (int sp = 0; sp < NSCAN; ++sp) {
        const float* p = Spart + (size_t)sp * 3 * HWN + pix;
        s0 += __builtin_nontemporal_load(reinterpret_cast<const f32x4*>(p));
        s1 += __builtin_nontemporal_load(reinterpret_cast<const f32x4*>(p + HWN));
        s2 += __builtin_nontemporal_load(reinterpret_cast<const f32x4*>(p + 2 * HWN));
    }
    f32x4 imp, unc, sow;
#pragma unroll
    for (int e = 0; e < 4; ++e) {
        sow[e] = 1e-10f + s0[e];
        imp[e] = s1[e] / sow[e];
        unc[e] = fmaf(-imp[e], s1[e], s2[e]);   // S2 - S1^2/sow
    }
    *reinterpret_cast<f32x4*>(out + pix) = imp;
    *reinterpret_cast<f32x4*>(out + HWN + pix) = unc;
    *reinterpret_cast<f32x4*>(out + 2 * HWN + pix) = sow;
}

extern "C" void kernel_launch(void* const* d_in, const int* in_sizes, int n_in,
                              void* d_out, int out_size, void* d_ws, size_t ws_size,
                              hipStream_t stream) {
    const float* img   = (const float*)d_in[0];
    const float* masks = (const float*)d_in[1];
    const float* Wt    = (const float*)d_in[2];
    float* out = (float*)d_out;

    char* ws = (char*)d_ws;
    unsigned short* Bpack = (unsigned short*)ws;                 // 12,845,056 B
    float* partial  = (float*)(ws + 12845056);                   // 25,690,112 B
    float* rep0part = partial;                                   // alias: consumed before gemm writes
    float* rep0     = (float*)(ws + 38535168);                   // 512 B
    float* sims     = (float*)(ws + 38535680);                   // 4,000 B
    float* Spart    = (float*)ws;                                // alias Bpack: gemm done by then (12,042,240 B)

    hipLaunchKernelGGL(k_encode,  dim3(784), dim3(256), 0, stream, img, Wt, Bpack, rep0part);
    hipLaunchKernelGGL(k_rep0red, dim3(128), dim3(256), 0, stream, rep0part, rep0);
    hipLaunchKernelGGL(k_gemm,    dim3(16, NSPLIT), dim3(256), 0, stream, masks, Bpack, partial);
    hipLaunchKernelGGL(k_sims,    dim3(NM), dim3(128), 0, stream, partial, rep0, sims);
    hipLaunchKernelGGL(k_colsums, dim3(49, NSCAN), dim3(256), 0, stream, masks, sims, Spart);
    hipLaunchKernelGGL(k_final,   dim3(49), dim3(256), 0, stream, Spart, out);
}